// Round 13
// baseline (341.505 us; speedup 1.0000x reference)
//
#include <hip/hip_runtime.h>
#include <math.h>

#define NN 100000
#define NE 1600000
#define BUCKETS ((NN + 255) >> 8)              // 391 buckets of 256 nodes
#define RTH 1024                                // threads in reorder/bhist blocks
#define RVPT 4                                  // edges per thread (4096 edges/block)

typedef short bf16x8 __attribute__((ext_vector_type(8)));
typedef float f32x4 __attribute__((ext_vector_type(4)));

__device__ inline float bsf(unsigned short u) { return __uint_as_float(((unsigned)u) << 16); }
__device__ inline unsigned short f2bs(float f) {           // RNE, matches np/hw bf16
    unsigned u = __float_as_uint(f);
    return (unsigned short)((u + 0x7fffu + ((u >> 16) & 1u)) >> 16);
}

// ---------------- CSR build (no scattered global atomics) ----------------
__global__ __launch_bounds__(RTH) void bhist_k(const int* __restrict__ dst,
                                               int* __restrict__ bhist) {
    __shared__ int bh[BUCKETS];
    for (int i = threadIdx.x; i < BUCKETS; i += RTH) bh[i] = 0;
    __syncthreads();
    int e0 = blockIdx.x * (RTH * RVPT) + threadIdx.x;
#pragma unroll
    for (int v = 0; v < RVPT; ++v) {
        int e = e0 + v * RTH;
        if (e < NE) atomicAdd(&bh[dst[e] >> 8], 1);
    }
    __syncthreads();
    for (int i = threadIdx.x; i < BUCKETS; i += RTH)
        if (bh[i]) atomicAdd(&bhist[i], bh[i]);
}

__global__ __launch_bounds__(512) void bscan_k(const int* __restrict__ bhist,
                                               int* __restrict__ bcur) {
    __shared__ int buf[512];
    int tid = threadIdx.x;
    int v = (tid < BUCKETS) ? bhist[tid] : 0;
    buf[tid] = v;
    __syncthreads();
    for (int off = 1; off < 512; off <<= 1) {
        int t = (tid >= off) ? buf[tid - off] : 0;
        __syncthreads();
        buf[tid] += t;
        __syncthreads();
    }
    if (tid < BUCKETS) bcur[tid] = buf[tid] - v;
}

__global__ __launch_bounds__(RTH) void reorder_k(const int* __restrict__ src,
                                                 const int* __restrict__ dst,
                                                 int* __restrict__ bcur,
                                                 unsigned long long* __restrict__ ebuf) {
    __shared__ int hist[BUCKETS];
    __shared__ int base[BUCKETS];
    int tid = threadIdx.x;
    for (int i = tid; i < BUCKETS; i += RTH) hist[i] = 0;
    __syncthreads();
    int e0 = blockIdx.x * (RTH * RVPT) + tid;
    unsigned long long pair[RVPT];
    int pr[RVPT];
#pragma unroll
    for (int v = 0; v < RVPT; ++v) {
        int e = e0 + v * RTH;
        if (e < NE) {
            int s = src[e], d = dst[e];
            pair[v] = ((unsigned long long)(unsigned)d << 32) | (unsigned)s;
            int b = d >> 8;
            int r = atomicAdd(&hist[b], 1);   // local rank < 4096, fits 12 bits
            pr[v] = (b << 12) | r;
        } else pr[v] = -1;
    }
    __syncthreads();
    for (int i = tid; i < BUCKETS; i += RTH)
        base[i] = hist[i] ? atomicAdd(&bcur[i], hist[i]) : 0;
    __syncthreads();
#pragma unroll
    for (int v = 0; v < RVPT; ++v) {
        if (pr[v] >= 0) {
            int b = pr[v] >> 12, r = pr[v] & 4095;
            ebuf[(size_t)base[b] + r] = pair[v];
        }
    }
}

__global__ __launch_bounds__(512) void pcsr_k(const unsigned long long* __restrict__ ebuf,
                                              const int* __restrict__ bend,
                                              int* __restrict__ row_ptr,
                                              int* __restrict__ col) {
    __shared__ int hist[256];
    __shared__ int wsum[4];
    int b = blockIdx.x;
    int tid = threadIdx.x;
    int beg = b ? bend[b - 1] : 0;
    int end = bend[b];

    if (tid < 256) hist[tid] = 0;
    __syncthreads();
    for (int e = beg + tid; e < end; e += 512)
        atomicAdd(&hist[(int)(ebuf[e] >> 32) & 255], 1);
    __syncthreads();

    int v = 0, excl = 0;
    if (tid < 256) {
        v = hist[tid];
        int lane = tid & 63, wid = tid >> 6;
        int s = v;
#pragma unroll
        for (int off = 1; off < 64; off <<= 1) {
            int t = __shfl_up(s, off);
            if (lane >= off) s += t;
        }
        if (lane == 63) wsum[wid] = s;
        excl = s - v;
    }
    __syncthreads();
    if (tid < 256) {
        int wid = tid >> 6;
        int prev = 0;
#pragma unroll
        for (int w = 0; w < 4; ++w) prev += (w < wid) ? wsum[w] : 0;
        excl += beg + prev;
        int node = b * 256 + tid;
        if (node < NN) row_ptr[node] = excl;
        if (node == NN - 1) row_ptr[NN] = excl + v;
    }
    __syncthreads();
    if (tid < 256) hist[tid] = excl;
    __syncthreads();
    for (int e = beg + tid; e < end; e += 512) {
        unsigned long long p = ebuf[e];
        int d = (int)(p >> 32);
        int pos = atomicAdd(&hist[d & 255], 1);
        col[pos] = (int)(p & 0xffffffffu);
    }
}

// ---------------- weight convert (all 3 layers, one launch) ----------------
__global__ __launch_bounds__(256) void wcvt_all_k(
    const float* __restrict__ Wl1, const float* __restrict__ Wr1,
    const float* __restrict__ Wl2, const float* __restrict__ Wr2,
    const float* __restrict__ Wl3, const float* __restrict__ Wr3,
    unsigned short* __restrict__ wt1, unsigned short* __restrict__ wt2,
    unsigned short* __restrict__ wt3) {
    int idx = blockIdx.x * 256 + threadIdx.x;
    if (idx < 4096) {                       // L1: [64][64]
        int j = idx >> 6, k = idx & 63;
        float v = (k < 32) ? Wl1[k * 64 + j] : Wr1[(k - 32) * 64 + j];
        wt1[idx] = f2bs(v);
    } else if (idx < 16384) {               // L2: [96][128]
        int t = idx - 4096;
        int j = t / 128, k = t - j * 128;
        float v = (k < 64) ? Wl2[k * 96 + j] : Wr2[(k - 64) * 96 + j];
        wt2[t] = f2bs(v);
    } else if (idx < 40960) {               // L3: [128][192]
        int t = idx - 16384;
        int j = t / 192, k = t - j * 192;
        float v = (k < 96) ? Wl3[k * 128 + j] : Wr3[(k - 96) * 128 + j];
        wt3[t] = f2bs(v);
    }
}

// ---------------- layer-0 aggregation + update (scalar, K=6) ----------------
__global__ __launch_bounds__(256) void agg0_k(const int* __restrict__ rp, const int* __restrict__ col,
                                              const float* __restrict__ x, unsigned short* __restrict__ magg) {
    int node = blockIdx.x * 4 + (threadIdx.x >> 6);
    int lane = threadIdx.x & 63;
    int fl = lane & 3, es = lane >> 2;
    int beg = rp[node], end = rp[node + 1];
    float acc = 0.0f;
    for (int e = beg + es; e < end; e += 16) {
        unsigned off = (unsigned)(col[e] * 3);
        if (fl < 3) acc += x[off + fl];
    }
    acc += __shfl(acc, lane + 32);
    acc += __shfl(acc, lane + 16);
    acc += __shfl(acc, lane + 8);
    acc += __shfl(acc, lane + 4);
    if (lane < 3) {
        float inv = 1.0f / fmaxf((float)(end - beg), 1.0f);
        magg[(size_t)node * 3 + lane] = f2bs(acc * inv);
    }
}

template<int DIN, int DOUT, int CT>
__global__ __launch_bounds__(256) void gemm_k(
    const unsigned short* __restrict__ magg, const float* __restrict__ hx,
    const float* __restrict__ Wl, const float* __restrict__ bl, const float* __restrict__ Wr,
    unsigned short* __restrict__ hout)
{
    __shared__ float sm[32][DIN + 1];
    __shared__ float sh[32][DIN + 1];

    int tx = threadIdx.x;
    int base = blockIdx.x * 32;

    for (int f = tx; f < 32 * 3; f += 256) {
        int n = f / 3, k = f - n * 3;
        sm[n][k] = bsf(magg[(size_t)(base + n) * 3 + k]);
        sh[n][k] = hx[(size_t)(base + n) * 3 + k];
    }
    __syncthreads();

    int ng = tx >> 5, cg = tx & 31;
    float acc[4][CT];
#pragma unroll
    for (int m = 0; m < 4; ++m)
#pragma unroll
        for (int c = 0; c < CT; ++c) acc[m][c] = bl[cg * CT + c];

#pragma unroll
    for (int k = 0; k < 3; ++k) {
        float wl[CT], wr[CT];
#pragma unroll
        for (int c = 0; c < CT; ++c) {
            wl[c] = Wl[(size_t)k * DOUT + cg * CT + c];
            wr[c] = Wr[(size_t)k * DOUT + cg * CT + c];
        }
#pragma unroll
        for (int m = 0; m < 4; ++m) {
            float mv = sm[ng * 4 + m][k];
            float hv = sh[ng * 4 + m][k];
#pragma unroll
            for (int c = 0; c < CT; ++c)
                acc[m][c] = fmaf(mv, wl[c], fmaf(hv, wr[c], acc[m][c]));
        }
    }

#pragma unroll
    for (int m = 0; m < 4; ++m)
#pragma unroll
        for (int c = 0; c < CT; ++c) {
            float v = fmaxf(acc[m][c], 0.0f);
            hout[(size_t)(base + ng * 4 + m) * DOUT + cg * CT + c] = f2bs(v);
        }
}

// ---------------- fused gather-mean + MFMA update (+ in-register final proj) ----------------
// block = 256 thr (4 waves) = 64 nodes; LDS = lA only (B read from global, L1/L2-broadcast).
// Phase 1: each wave gathers its 16 nodes (agg_k inner structure, 4-deep load pipeline),
//          mean -> lA[n][0..DIN), self h staged -> lA[n][DIN..2*DIN).
// Phase 2: MFMA over K2=2*DIN; epilogue relu+bias -> hout, or in-register 128->4+sigmoid.
template<int DIN, int DOUT, bool FINAL>
__global__ __launch_bounds__(256) void fused_k(
    const int* __restrict__ rp, const int* __restrict__ col,
    const unsigned short* __restrict__ h,
    const unsigned short* __restrict__ Wt, const float* __restrict__ bl,
    const float* __restrict__ Wf, const float* __restrict__ bfi,
    unsigned short* __restrict__ hout, float* __restrict__ out)
{
    constexpr int K2  = 2 * DIN;
    constexpr int STR = K2 + 8;
    constexpr int NT  = DOUT / 16;
    constexpr int KS  = K2 / 32;
    constexpr int FL  = DIN / 8;       // 16B feature lanes per row
    constexpr int EPW = 64 / FL;       // edge slots (5 for DIN=96: lanes 60-63 idle)
    __shared__ unsigned short lA[64 * STR];

    int tx = threadIdx.x;
    int lane = tx & 63;
    int wm = tx >> 6;
    int base = blockIdx.x * 64;

    // stage self h (coalesced)
    constexpr int CPM = DIN / 8;
    for (int c = tx; c < 64 * CPM; c += 256) {
        int n = c / CPM, o = (c - n * CPM) * 8;
        int node = base + n;
        uint4 vh = make_uint4(0, 0, 0, 0);
        if (node < NN) vh = *(const uint4*)(h + (size_t)node * DIN + o);
        *(uint4*)(lA + n * STR + DIN + o) = vh;
    }

    // gather mean for this wave's 16 nodes
    int fl = lane % FL;
    int es = lane / FL;
    for (int i = 0; i < 16; ++i) {
        int n = wm * 16 + i;
        int node = base + n;
        int beg = 0, end = 0;
        if (node < NN) { beg = rp[node]; end = rp[node + 1]; }

        float a[8];
#pragma unroll
        for (int j = 0; j < 8; ++j) a[j] = 0.0f;

        if (es < EPW) {
            for (int e = beg + es; e < end; e += 4 * EPW) {
                int e1 = e + EPW, e2 = e + 2 * EPW, e3 = e + 3 * EPW;
                bool b1 = e1 < end, b2 = e2 < end, b3 = e3 < end;
                unsigned o0 = (unsigned)(col[e] * DIN);
                unsigned o1 = (unsigned)(col[b1 ? e1 : e] * DIN);
                unsigned o2 = (unsigned)(col[b2 ? e2 : e] * DIN);
                unsigned o3 = (unsigned)(col[b3 ? e3 : e] * DIN);
                uint4 v0 = *(const uint4*)(h + o0 + fl * 8);
                uint4 v1 = *(const uint4*)(h + o1 + fl * 8);
                uint4 v2 = *(const uint4*)(h + o2 + fl * 8);
                uint4 v3 = *(const uint4*)(h + o3 + fl * 8);
                float m1 = b1 ? 1.0f : 0.0f;
                float m2 = b2 ? 1.0f : 0.0f;
                float m3 = b3 ? 1.0f : 0.0f;
                const unsigned short* p0 = (const unsigned short*)&v0;
                const unsigned short* p1 = (const unsigned short*)&v1;
                const unsigned short* p2 = (const unsigned short*)&v2;
                const unsigned short* p3 = (const unsigned short*)&v3;
#pragma unroll
                for (int j = 0; j < 8; ++j) {
                    a[j] += bsf(p0[j]);
                    a[j] = fmaf(bsf(p1[j]), m1, a[j]);
                    a[j] = fmaf(bsf(p2[j]), m2, a[j]);
                    a[j] = fmaf(bsf(p3[j]), m3, a[j]);
                }
            }
        }

        if constexpr (FL == 4) {
#pragma unroll
            for (int j = 0; j < 8; ++j) {
                a[j] += __shfl(a[j], lane + 4);
                a[j] += __shfl(a[j], lane + 8);
                a[j] += __shfl(a[j], lane + 16);
                a[j] += __shfl(a[j], lane + 32);
            }
        } else if constexpr (FL == 8) {
#pragma unroll
            for (int j = 0; j < 8; ++j) {
                a[j] += __shfl(a[j], lane + 8);
                a[j] += __shfl(a[j], lane + 16);
                a[j] += __shfl(a[j], lane + 32);
            }
        } else {                        // FL==12, EPW=5: es0+es1+es2+es3 via +12/+24, es4 via +48
#pragma unroll
            for (int j = 0; j < 8; ++j) {
                float g4 = __shfl(a[j], lane + 48);
                a[j] += __shfl(a[j], lane + 12);
                a[j] += __shfl(a[j], lane + 24);
                a[j] += g4;
            }
        }

        if (lane < FL) {
            float inv = 1.0f / fmaxf((float)(end - beg), 1.0f);
            unsigned short o8[8];
#pragma unroll
            for (int j = 0; j < 8; ++j) o8[j] = f2bs(a[j] * inv);
            *(uint4*)(lA + n * STR + fl * 8) = *(const uint4*)o8;
        }
    }
    __syncthreads();

    // MFMA: A from lA, B from global (L1/L2-resident broadcast)
    int r16 = lane & 15, kg = lane >> 4;

    f32x4 acc[NT];
#pragma unroll
    for (int t = 0; t < NT; ++t) acc[t] = (f32x4){0.0f, 0.0f, 0.0f, 0.0f};

#pragma unroll
    for (int kk = 0; kk < KS; ++kk) {
        bf16x8 a = *(const bf16x8*)(lA + (wm * 16 + r16) * STR + kk * 32 + kg * 8);
#pragma unroll
        for (int t = 0; t < NT; ++t) {
            bf16x8 b = *(const bf16x8*)(Wt + (size_t)(t * 16 + r16) * K2 + kk * 32 + kg * 8);
            acc[t] = __builtin_amdgcn_mfma_f32_16x16x32_bf16(a, b, acc[t], 0, 0, 0);
        }
    }

    if (!FINAL) {
#pragma unroll
        for (int t = 0; t < NT; ++t)
#pragma unroll
            for (int r = 0; r < 4; ++r) {
                int node = base + wm * 16 + kg * 4 + r;      // C/D: row=(lane>>4)*4+reg
                int colj = t * 16 + r16;                      //      col=lane&15
                float v = fmaxf(acc[t][r] + bl[colj], 0.0f);
                if (node < NN) hout[(size_t)node * DOUT + colj] = f2bs(v);
            }
    } else {
        // in-register final: per-lane partials over its 8 cols, then shfl_xor over r16 group
        float p[4][4];
#pragma unroll
        for (int r = 0; r < 4; ++r)
#pragma unroll
            for (int c = 0; c < 4; ++c) p[r][c] = 0.0f;
#pragma unroll
        for (int t = 0; t < NT; ++t) {
            int colj = t * 16 + r16;
            float bv = bl[colj];
#pragma unroll
            for (int r = 0; r < 4; ++r) {
                float v = fmaxf(acc[t][r] + bv, 0.0f);
#pragma unroll
                for (int c = 0; c < 4; ++c)
                    p[r][c] = fmaf(v, Wf[colj * 4 + c], p[r][c]);
            }
        }
#pragma unroll
        for (int r = 0; r < 4; ++r)
#pragma unroll
            for (int c = 0; c < 4; ++c) {
                p[r][c] += __shfl_xor(p[r][c], 1);
                p[r][c] += __shfl_xor(p[r][c], 2);
                p[r][c] += __shfl_xor(p[r][c], 4);
                p[r][c] += __shfl_xor(p[r][c], 8);
            }
        if (r16 == 0) {
#pragma unroll
            for (int r = 0; r < 4; ++r) {
                int node = base + wm * 16 + kg * 4 + r;
                if (node < NN) {
#pragma unroll
                    for (int c = 0; c < 4; ++c)
                        out[(size_t)node * 4 + c] = 1.0f / (1.0f + expf(-(p[r][c] + bfi[c])));
                }
            }
        }
    }
}

extern "C" void kernel_launch(void* const* d_in, const int* in_sizes, int n_in,
                              void* d_out, int out_size, void* d_ws, size_t ws_size,
                              hipStream_t stream) {
    const float* x   = (const float*)d_in[0];
    const int*   ei  = (const int*)d_in[1];
    const int*   src = ei;
    const int*   dst = ei + NE;
    const float* Wl0 = (const float*)d_in[2];
    const float* bl0 = (const float*)d_in[3];
    const float* Wr0 = (const float*)d_in[4];
    const float* Wl1 = (const float*)d_in[5];
    const float* bl1 = (const float*)d_in[6];
    const float* Wr1 = (const float*)d_in[7];
    const float* Wl2 = (const float*)d_in[8];
    const float* bl2 = (const float*)d_in[9];
    const float* Wr2 = (const float*)d_in[10];
    const float* Wl3 = (const float*)d_in[11];
    const float* bl3 = (const float*)d_in[12];
    const float* Wr3 = (const float*)d_in[13];
    const float* Wf  = (const float*)d_in[14];
    const float* bf  = (const float*)d_in[15];
    float* out = (float*)d_out;

    // ws (ints): row_ptr[NN+2] | bhist[512] | bcur[512] | col[NE] | pad -> 64B-aligned bf16 region
    size_t ints = (size_t)(NN + 2) + 512 + 512 + NE;
    ints = (ints + 15) & ~(size_t)15;
    size_t need = ints * 4 + (size_t)NN * (96 + 32 + 64 + 96) * 2
                + (size_t)(64 * 64 + 96 * 128 + 128 * 192) * 2;
    if (ws_size < need) return;

    int* row_ptr = (int*)d_ws;
    int* bhist   = row_ptr + NN + 2;
    int* bcur    = bhist + 512;
    int* col     = bcur + 512;
    unsigned short* magg = (unsigned short*)((char*)d_ws + ints * 4);   // L0 mean (3/node)
    unsigned long long* ebuf = (unsigned long long*)magg;    // dead before magg is born
    unsigned short* h1   = magg + (size_t)NN * 96;
    unsigned short* h2   = h1 + (size_t)NN * 32;
    unsigned short* h3   = h2 + (size_t)NN * 64;
    unsigned short* wt1  = h3 + (size_t)NN * 96;
    unsigned short* wt2  = wt1 + 64 * 64;
    unsigned short* wt3  = wt2 + 96 * 128;

    // weight conversion (one launch)
    wcvt_all_k<<<160, 256, 0, stream>>>(Wl1, Wr1, Wl2, Wr2, Wl3, Wr3, wt1, wt2, wt3);

    // CSR build
    hipMemsetAsync(bhist, 0, 512 * sizeof(int), stream);
    const int EB = (NE + RTH * RVPT - 1) / (RTH * RVPT);    // 391
    bhist_k<<<EB, RTH, 0, stream>>>(dst, bhist);
    bscan_k<<<1, 512, 0, stream>>>(bhist, bcur);
    reorder_k<<<EB, RTH, 0, stream>>>(src, dst, bcur, ebuf);
    pcsr_k<<<BUCKETS, 512, 0, stream>>>(ebuf, bcur, row_ptr, col);

    const int MG = (NN + 63) / 64;   // 1563

    // layer 0: x(3) -> h1(32)  (scalar, K=6)
    agg0_k<<<NN / 4, 256, 0, stream>>>(row_ptr, col, x, magg);
    gemm_k<3, 32, 1><<<NN / 32, 256, 0, stream>>>(magg, x, Wl0, bl0, Wr0, h1);

    // layer 1: h1(32) -> h2(64)   (fused gather + MFMA)
    fused_k<32, 64, false><<<MG, 256, 0, stream>>>(
        row_ptr, col, h1, wt1, bl1, nullptr, nullptr, h2, nullptr);

    // layer 2: h2(64) -> h3(96)
    fused_k<64, 96, false><<<MG, 256, 0, stream>>>(
        row_ptr, col, h2, wt2, bl2, nullptr, nullptr, h3, nullptr);

    // layer 3 + final: h3(96) -> [128] -> sigmoid -> out(4)
    fused_k<96, 128, true><<<MG, 256, 0, stream>>>(
        row_ptr, col, h3, wt3, bl3, Wf, bf, nullptr, out);
}

// Round 14
// 289.925 us; speedup vs baseline: 1.1779x; 1.1779x over previous
//
#include <hip/hip_runtime.h>
#include <math.h>

#define NN 100000
#define NE 1600000
#define BUCKETS ((NN + 255) >> 8)              // 391 buckets of 256 nodes
#define RTH 1024                                // threads in reorder/bhist blocks
#define RVPT 4                                  // edges per thread (4096 edges/block)

typedef short bf16x8 __attribute__((ext_vector_type(8)));
typedef float f32x4 __attribute__((ext_vector_type(4)));
typedef float f32x2 __attribute__((ext_vector_type(2)));

__device__ inline float bsf(unsigned short u) { return __uint_as_float(((unsigned)u) << 16); }
__device__ inline unsigned short f2bs(float f) {           // RNE, matches np/hw bf16
    unsigned u = __float_as_uint(f);
    return (unsigned short)((u + 0x7fffu + ((u >> 16) & 1u)) >> 16);
}
// unpack one u32 (2 bf16) into f32x2 {lo, hi}
__device__ inline f32x2 bs2(unsigned w) {
    f32x2 r;
    r.x = __uint_as_float(w << 16);
    r.y = __uint_as_float(w & 0xffff0000u);
    return r;
}

// ---------------- CSR build (no scattered global atomics) ----------------
__global__ __launch_bounds__(RTH) void bhist_k(const int* __restrict__ dst,
                                               int* __restrict__ bhist) {
    __shared__ int bh[BUCKETS];
    for (int i = threadIdx.x; i < BUCKETS; i += RTH) bh[i] = 0;
    __syncthreads();
    int e0 = blockIdx.x * (RTH * RVPT) + threadIdx.x;
#pragma unroll
    for (int v = 0; v < RVPT; ++v) {
        int e = e0 + v * RTH;
        if (e < NE) atomicAdd(&bh[dst[e] >> 8], 1);
    }
    __syncthreads();
    for (int i = threadIdx.x; i < BUCKETS; i += RTH)
        if (bh[i]) atomicAdd(&bhist[i], bh[i]);
}

__global__ __launch_bounds__(512) void bscan_k(const int* __restrict__ bhist,
                                               int* __restrict__ bcur) {
    __shared__ int buf[512];
    int tid = threadIdx.x;
    int v = (tid < BUCKETS) ? bhist[tid] : 0;
    buf[tid] = v;
    __syncthreads();
    for (int off = 1; off < 512; off <<= 1) {
        int t = (tid >= off) ? buf[tid - off] : 0;
        __syncthreads();
        buf[tid] += t;
        __syncthreads();
    }
    if (tid < BUCKETS) bcur[tid] = buf[tid] - v;
}

__global__ __launch_bounds__(RTH) void reorder_k(const int* __restrict__ src,
                                                 const int* __restrict__ dst,
                                                 int* __restrict__ bcur,
                                                 unsigned long long* __restrict__ ebuf) {
    __shared__ int hist[BUCKETS];
    __shared__ int base[BUCKETS];
    int tid = threadIdx.x;
    for (int i = tid; i < BUCKETS; i += RTH) hist[i] = 0;
    __syncthreads();
    int e0 = blockIdx.x * (RTH * RVPT) + tid;
    unsigned long long pair[RVPT];
    int pr[RVPT];
#pragma unroll
    for (int v = 0; v < RVPT; ++v) {
        int e = e0 + v * RTH;
        if (e < NE) {
            int s = src[e], d = dst[e];
            pair[v] = ((unsigned long long)(unsigned)d << 32) | (unsigned)s;
            int b = d >> 8;
            int r = atomicAdd(&hist[b], 1);   // local rank < 4096, fits 12 bits
            pr[v] = (b << 12) | r;
        } else pr[v] = -1;
    }
    __syncthreads();
    for (int i = tid; i < BUCKETS; i += RTH)
        base[i] = hist[i] ? atomicAdd(&bcur[i], hist[i]) : 0;
    __syncthreads();
#pragma unroll
    for (int v = 0; v < RVPT; ++v) {
        if (pr[v] >= 0) {
            int b = pr[v] >> 12, r = pr[v] & 4095;
            ebuf[(size_t)base[b] + r] = pair[v];
        }
    }
}

__global__ __launch_bounds__(512) void pcsr_k(const unsigned long long* __restrict__ ebuf,
                                              const int* __restrict__ bend,
                                              int* __restrict__ row_ptr,
                                              int* __restrict__ col) {
    __shared__ int hist[256];
    __shared__ int wsum[4];
    int b = blockIdx.x;
    int tid = threadIdx.x;
    int beg = b ? bend[b - 1] : 0;
    int end = bend[b];

    if (tid < 256) hist[tid] = 0;
    __syncthreads();
    for (int e = beg + tid; e < end; e += 512)
        atomicAdd(&hist[(int)(ebuf[e] >> 32) & 255], 1);
    __syncthreads();

    int v = 0, excl = 0;
    if (tid < 256) {
        v = hist[tid];
        int lane = tid & 63, wid = tid >> 6;
        int s = v;
#pragma unroll
        for (int off = 1; off < 64; off <<= 1) {
            int t = __shfl_up(s, off);
            if (lane >= off) s += t;
        }
        if (lane == 63) wsum[wid] = s;
        excl = s - v;
    }
    __syncthreads();
    if (tid < 256) {
        int wid = tid >> 6;
        int prev = 0;
#pragma unroll
        for (int w = 0; w < 4; ++w) prev += (w < wid) ? wsum[w] : 0;
        excl += beg + prev;
        int node = b * 256 + tid;
        if (node < NN) row_ptr[node] = excl;
        if (node == NN - 1) row_ptr[NN] = excl + v;
    }
    __syncthreads();
    if (tid < 256) hist[tid] = excl;
    __syncthreads();
    for (int e = beg + tid; e < end; e += 512) {
        unsigned long long p = ebuf[e];
        int d = (int)(p >> 32);
        int pos = atomicAdd(&hist[d & 255], 1);
        col[pos] = (int)(p & 0xffffffffu);
    }
}

// ---------------- weight convert (all 3 layers, one launch) ----------------
__global__ __launch_bounds__(256) void wcvt_all_k(
    const float* __restrict__ Wl1, const float* __restrict__ Wr1,
    const float* __restrict__ Wl2, const float* __restrict__ Wr2,
    const float* __restrict__ Wl3, const float* __restrict__ Wr3,
    unsigned short* __restrict__ wt1, unsigned short* __restrict__ wt2,
    unsigned short* __restrict__ wt3) {
    int idx = blockIdx.x * 256 + threadIdx.x;
    if (idx < 4096) {                       // L1: [64][64]
        int j = idx >> 6, k = idx & 63;
        float v = (k < 32) ? Wl1[k * 64 + j] : Wr1[(k - 32) * 64 + j];
        wt1[idx] = f2bs(v);
    } else if (idx < 16384) {               // L2: [96][128]
        int t = idx - 4096;
        int j = t / 128, k = t - j * 128;
        float v = (k < 64) ? Wl2[k * 96 + j] : Wr2[(k - 64) * 96 + j];
        wt2[t] = f2bs(v);
    } else if (idx < 40960) {               // L3: [128][192]
        int t = idx - 16384;
        int j = t / 192, k = t - j * 192;
        float v = (k < 96) ? Wl3[k * 128 + j] : Wr3[(k - 96) * 128 + j];
        wt3[t] = f2bs(v);
    }
}

// ---------------- layer-0 aggregation ----------------
__global__ __launch_bounds__(256) void agg0_k(const int* __restrict__ rp, const int* __restrict__ col,
                                              const float* __restrict__ x, unsigned short* __restrict__ magg) {
    int node = blockIdx.x * 4 + (threadIdx.x >> 6);
    int lane = threadIdx.x & 63;
    int fl = lane & 3, es = lane >> 2;
    int beg = rp[node], end = rp[node + 1];
    float acc = 0.0f;
    for (int e = beg + es; e < end; e += 16) {
        unsigned off = (unsigned)(col[e] * 3);
        if (fl < 3) acc += x[off + fl];
    }
    acc += __shfl(acc, lane + 32);
    acc += __shfl(acc, lane + 16);
    acc += __shfl(acc, lane + 8);
    acc += __shfl(acc, lane + 4);
    if (lane < 3) {
        float inv = 1.0f / fmaxf((float)(end - beg), 1.0f);
        magg[(size_t)node * 3 + lane] = f2bs(acc * inv);
    }
}

// ---------------- generic aggregation: hb bf16 [N,DIN] -> magg bf16 [N,DIN] ----------------
// wave per node; FL lanes x 16B cover a row; EPW edge slots; 4-deep load pipeline.
// Packed bf16->f32x2 unpack (shl / and) + f32x2 fma -> v_pk_fma_f32 on CDNA4.
template<int DIN, int FL, int EPW>
__global__ __launch_bounds__(256) void agg_k(const int* __restrict__ rp, const int* __restrict__ col,
                                             const unsigned short* __restrict__ hb,
                                             unsigned short* __restrict__ magg) {
    int node = blockIdx.x * 4 + (threadIdx.x >> 6);
    int lane = threadIdx.x & 63;
    int fl = lane % FL;
    int es = lane / FL;
    int beg = rp[node], end = rp[node + 1];

    f32x2 a2[4];
#pragma unroll
    for (int i = 0; i < 4; ++i) a2[i] = (f32x2){0.0f, 0.0f};

    if (es < EPW) {
        for (int e = beg + es; e < end; e += 4 * EPW) {
            int e1 = e + EPW, e2 = e + 2 * EPW, e3 = e + 3 * EPW;
            bool b1 = e1 < end, b2 = e2 < end, b3 = e3 < end;
            unsigned o0 = (unsigned)(col[e] * DIN);
            unsigned o1 = (unsigned)(col[b1 ? e1 : e] * DIN);
            unsigned o2 = (unsigned)(col[b2 ? e2 : e] * DIN);
            unsigned o3 = (unsigned)(col[b3 ? e3 : e] * DIN);
            uint4 v0 = *(const uint4*)(hb + o0 + fl * 8);
            uint4 v1 = *(const uint4*)(hb + o1 + fl * 8);
            uint4 v2 = *(const uint4*)(hb + o2 + fl * 8);
            uint4 v3 = *(const uint4*)(hb + o3 + fl * 8);
            f32x2 m1 = (f32x2){b1 ? 1.0f : 0.0f, b1 ? 1.0f : 0.0f};
            f32x2 m2 = (f32x2){b2 ? 1.0f : 0.0f, b2 ? 1.0f : 0.0f};
            f32x2 m3 = (f32x2){b3 ? 1.0f : 0.0f, b3 ? 1.0f : 0.0f};
            const unsigned* w0 = (const unsigned*)&v0;
            const unsigned* w1 = (const unsigned*)&v1;
            const unsigned* w2 = (const unsigned*)&v2;
            const unsigned* w3 = (const unsigned*)&v3;
#pragma unroll
            for (int i = 0; i < 4; ++i) {
                a2[i] += bs2(w0[i]);            // v_pk_add_f32
                a2[i] += bs2(w1[i]) * m1;       // v_pk_fma_f32
                a2[i] += bs2(w2[i]) * m2;
                a2[i] += bs2(w3[i]) * m3;
            }
        }
    }

    // reduce across EPW groups (stride FL)
    if constexpr (FL == 4) {        // EPW=16
#pragma unroll
        for (int i = 0; i < 4; ++i) {
#pragma unroll
            for (int j = 0; j < 2; ++j) {
                a2[i][j] += __shfl(a2[i][j], lane + 4);
                a2[i][j] += __shfl(a2[i][j], lane + 8);
                a2[i][j] += __shfl(a2[i][j], lane + 16);
                a2[i][j] += __shfl(a2[i][j], lane + 32);
            }
        }
    } else if constexpr (FL == 8) { // EPW=8
#pragma unroll
        for (int i = 0; i < 4; ++i) {
#pragma unroll
            for (int j = 0; j < 2; ++j) {
                a2[i][j] += __shfl(a2[i][j], lane + 8);
                a2[i][j] += __shfl(a2[i][j], lane + 16);
                a2[i][j] += __shfl(a2[i][j], lane + 32);
            }
        }
    } else {                        // FL==12, EPW=5
#pragma unroll
        for (int i = 0; i < 4; ++i) {
#pragma unroll
            for (int j = 0; j < 2; ++j) {
                float g4 = __shfl(a2[i][j], lane + 48);
                a2[i][j] += __shfl(a2[i][j], lane + 12);
                a2[i][j] += __shfl(a2[i][j], lane + 24);
                a2[i][j] += g4;
            }
        }
    }

    if (lane < FL) {
        float inv = 1.0f / fmaxf((float)(end - beg), 1.0f);
        unsigned short o[8];
#pragma unroll
        for (int i = 0; i < 4; ++i) {
            o[2 * i]     = f2bs(a2[i].x * inv);
            o[2 * i + 1] = f2bs(a2[i].y * inv);
        }
        *(uint4*)(magg + (size_t)node * DIN + fl * 8) = *(const uint4*)o;
    }
}

// ---------------- scalar update (layer 0 only, K=6) ----------------
template<int DIN, int DOUT, int CT>
__global__ __launch_bounds__(256) void gemm_k(
    const unsigned short* __restrict__ magg, const float* __restrict__ hx,
    const float* __restrict__ Wl, const float* __restrict__ bl, const float* __restrict__ Wr,
    unsigned short* __restrict__ hout)
{
    __shared__ float sm[32][DIN + 1];
    __shared__ float sh[32][DIN + 1];

    int tx = threadIdx.x;
    int base = blockIdx.x * 32;

    for (int f = tx; f < 32 * 3; f += 256) {
        int n = f / 3, k = f - n * 3;
        sm[n][k] = bsf(magg[(size_t)(base + n) * 3 + k]);
        sh[n][k] = hx[(size_t)(base + n) * 3 + k];
    }
    __syncthreads();

    int ng = tx >> 5, cg = tx & 31;
    float acc[4][CT];
#pragma unroll
    for (int m = 0; m < 4; ++m)
#pragma unroll
        for (int c = 0; c < CT; ++c) acc[m][c] = bl[cg * CT + c];

#pragma unroll
    for (int k = 0; k < 3; ++k) {
        float wl[CT], wr[CT];
#pragma unroll
        for (int c = 0; c < CT; ++c) {
            wl[c] = Wl[(size_t)k * DOUT + cg * CT + c];
            wr[c] = Wr[(size_t)k * DOUT + cg * CT + c];
        }
#pragma unroll
        for (int m = 0; m < 4; ++m) {
            float mv = sm[ng * 4 + m][k];
            float hv = sh[ng * 4 + m][k];
#pragma unroll
            for (int c = 0; c < CT; ++c)
                acc[m][c] = fmaf(mv, wl[c], fmaf(hv, wr[c], acc[m][c]));
        }
    }

#pragma unroll
    for (int m = 0; m < 4; ++m)
#pragma unroll
        for (int c = 0; c < CT; ++c) {
            float v = fmaxf(acc[m][c], 0.0f);
            hout[(size_t)(base + ng * 4 + m) * DOUT + cg * CT + c] = f2bs(v);
        }
}

// ---------------- MFMA update: relu([magg|h] @ Wt^T + bl), optional fused final ----------------
template<int DIN, int DOUT, bool FINAL>
__global__ __launch_bounds__(256) void mgemm_k(
    const unsigned short* __restrict__ magg, const unsigned short* __restrict__ h,
    const unsigned short* __restrict__ Wt, const float* __restrict__ bl,
    const float* __restrict__ Wf, const float* __restrict__ bfi,
    unsigned short* __restrict__ hout, float* __restrict__ out)
{
    constexpr int K2  = 2 * DIN;
    constexpr int STR = K2 + 8;
    constexpr int NT  = DOUT / 16;
    constexpr int KS  = K2 / 32;
    __shared__ unsigned short lA[64 * STR];
    __shared__ unsigned short lB[DOUT * STR];

    int tx = threadIdx.x;
    int base = blockIdx.x * 64;

    constexpr int CPM = DIN / 8;
    for (int c = tx; c < 64 * CPM; c += 256) {
        int n = c / CPM, o = (c - n * CPM) * 8;
        int node = base + n;
        uint4 vm = make_uint4(0, 0, 0, 0), vh = vm;
        if (node < NN) {
            vm = *(const uint4*)(magg + (size_t)node * DIN + o);
            vh = *(const uint4*)(h    + (size_t)node * DIN + o);
        }
        *(uint4*)(lA + n * STR + o)       = vm;
        *(uint4*)(lA + n * STR + DIN + o) = vh;
    }
    constexpr int CPW = K2 / 8;
    for (int c = tx; c < DOUT * CPW; c += 256) {
        int j = c / CPW, o = (c - j * CPW) * 8;
        *(uint4*)(lB + j * STR + o) = *(const uint4*)(Wt + (size_t)j * K2 + o);
    }
    __syncthreads();

    int lane = tx & 63;
    int wm = tx >> 6;
    int r16 = lane & 15, kg = lane >> 4;

    f32x4 acc[NT];
#pragma unroll
    for (int t = 0; t < NT; ++t) acc[t] = (f32x4){0.0f, 0.0f, 0.0f, 0.0f};

#pragma unroll
    for (int kk = 0; kk < KS; ++kk) {
        bf16x8 a = *(const bf16x8*)(lA + (wm * 16 + r16) * STR + kk * 32 + kg * 8);
#pragma unroll
        for (int t = 0; t < NT; ++t) {
            bf16x8 b = *(const bf16x8*)(lB + (t * 16 + r16) * STR + kk * 32 + kg * 8);
            acc[t] = __builtin_amdgcn_mfma_f32_16x16x32_bf16(a, b, acc[t], 0, 0, 0);
        }
    }

    if (!FINAL) {
#pragma unroll
        for (int t = 0; t < NT; ++t)
#pragma unroll
            for (int r = 0; r < 4; ++r) {
                int node = base + wm * 16 + kg * 4 + r;
                int colj = t * 16 + r16;
                float v = fmaxf(acc[t][r] + bl[colj], 0.0f);
                if (node < NN) hout[(size_t)node * DOUT + colj] = f2bs(v);
            }
    } else {
        __syncthreads();
        float* s4 = (float*)lB;
#pragma unroll
        for (int t = 0; t < NT; ++t)
#pragma unroll
            for (int r = 0; r < 4; ++r) {
                int nl = wm * 16 + kg * 4 + r;
                int colj = t * 16 + r16;
                s4[nl * 129 + colj] = fmaxf(acc[t][r] + bl[colj], 0.0f);
            }
        __syncthreads();
        int nl = tx >> 2, c = tx & 3;
        int node = base + nl;
        if (node < NN) {
            float a = bfi[c];
#pragma unroll 8
            for (int k = 0; k < 128; ++k)
                a = fmaf(s4[nl * 129 + k], Wf[k * 4 + c], a);
            out[(size_t)node * 4 + c] = 1.0f / (1.0f + expf(-a));
        }
    }
}

extern "C" void kernel_launch(void* const* d_in, const int* in_sizes, int n_in,
                              void* d_out, int out_size, void* d_ws, size_t ws_size,
                              hipStream_t stream) {
    const float* x   = (const float*)d_in[0];
    const int*   ei  = (const int*)d_in[1];
    const int*   src = ei;
    const int*   dst = ei + NE;
    const float* Wl0 = (const float*)d_in[2];
    const float* bl0 = (const float*)d_in[3];
    const float* Wr0 = (const float*)d_in[4];
    const float* Wl1 = (const float*)d_in[5];
    const float* bl1 = (const float*)d_in[6];
    const float* Wr1 = (const float*)d_in[7];
    const float* Wl2 = (const float*)d_in[8];
    const float* bl2 = (const float*)d_in[9];
    const float* Wr2 = (const float*)d_in[10];
    const float* Wl3 = (const float*)d_in[11];
    const float* bl3 = (const float*)d_in[12];
    const float* Wr3 = (const float*)d_in[13];
    const float* Wf  = (const float*)d_in[14];
    const float* bf  = (const float*)d_in[15];
    float* out = (float*)d_out;

    // ws (ints): row_ptr[NN+2] | bhist[512] | bcur[512] | col[NE] | pad -> 64B-aligned bf16 region
    size_t ints = (size_t)(NN + 2) + 512 + 512 + NE;
    ints = (ints + 15) & ~(size_t)15;
    size_t need = ints * 4 + (size_t)NN * (96 + 32 + 64 + 96) * 2
                + (size_t)(64 * 64 + 96 * 128 + 128 * 192) * 2;
    if (ws_size < need) return;

    int* row_ptr = (int*)d_ws;
    int* bhist   = row_ptr + NN + 2;
    int* bcur    = bhist + 512;
    int* col     = bcur + 512;
    unsigned short* magg = (unsigned short*)((char*)d_ws + ints * 4);
    unsigned long long* ebuf = (unsigned long long*)magg;    // dead before magg is born
    unsigned short* h1   = magg + (size_t)NN * 96;
    unsigned short* h2   = h1 + (size_t)NN * 32;
    unsigned short* h3   = h2 + (size_t)NN * 64;
    unsigned short* wt1  = h3 + (size_t)NN * 96;
    unsigned short* wt2  = wt1 + 64 * 64;
    unsigned short* wt3  = wt2 + 96 * 128;

    // weight conversion (one launch)
    wcvt_all_k<<<160, 256, 0, stream>>>(Wl1, Wr1, Wl2, Wr2, Wl3, Wr3, wt1, wt2, wt3);

    // CSR build
    hipMemsetAsync(bhist, 0, 512 * sizeof(int), stream);
    const int EB = (NE + RTH * RVPT - 1) / (RTH * RVPT);    // 391
    bhist_k<<<EB, RTH, 0, stream>>>(dst, bhist);
    bscan_k<<<1, 512, 0, stream>>>(bhist, bcur);
    reorder_k<<<EB, RTH, 0, stream>>>(src, dst, bcur, ebuf);
    pcsr_k<<<BUCKETS, 512, 0, stream>>>(ebuf, bcur, row_ptr, col);

    const int AGRID = NN / 4;
    const int MG    = (NN + 63) / 64;

    // layer 0: x(3) -> h1(32)  (scalar, K=6)
    agg0_k<<<AGRID, 256, 0, stream>>>(row_ptr, col, x, magg);
    gemm_k<3, 32, 1><<<NN / 32, 256, 0, stream>>>(magg, x, Wl0, bl0, Wr0, h1);

    // layer 1: h1(32) -> h2(64)
    agg_k<32, 4, 16><<<AGRID, 256, 0, stream>>>(row_ptr, col, h1, magg);
    mgemm_k<32, 64, false><<<MG, 256, 0, stream>>>(
        magg, h1, wt1, bl1, nullptr, nullptr, h2, nullptr);

    // layer 2: h2(64) -> h3(96)
    agg_k<64, 8, 8><<<AGRID, 256, 0, stream>>>(row_ptr, col, h2, magg);
    mgemm_k<64, 96, false><<<MG, 256, 0, stream>>>(
        magg, h2, wt2, bl2, nullptr, nullptr, h3, nullptr);

    // layer 3 + final: h3(96) -> [128] -> out(4)
    agg_k<96, 12, 5><<<AGRID, 256, 0, stream>>>(row_ptr, col, h3, magg);
    mgemm_k<96, 128, true><<<MG, 256, 0, stream>>>(
        magg, h3, wt3, bl3, Wf, bf, nullptr, out);
}